// Round 4
// baseline (2818.063 us; speedup 1.0000x reference)
//
#include <hip/hip_runtime.h>
#include <hip/hip_bf16.h>

// Problem constants
#define B_  8
#define C_  256
#define H_  96
#define W_  96
#define G_  8
#define CPG 32          // C_/G_
#define KK  9           // 3x3 taps
#define O_  72          // G_*KK conv out channels
#define HW  9216        // H_*W_
#define NPX 73728       // B_*HW (BN population per channel)
#define WSTR 84         // wT per-(og,c) stride: 81 used, padded to 84 (336B, 16B-aligned)

// ---------------- K0: weight transpose  w[o][c][tap] -> wT[og][c][oo*9+tap] ----------------
__global__ __launch_bounds__(256) void wprep_kernel(const float* __restrict__ w,
                                                    float* __restrict__ wt) {
    int idx = blockIdx.x * 256 + threadIdx.x;        // O_*C_*KK = 165888
    if (idx >= O_ * C_ * KK) return;
    int tap = idx % 9;
    int rem = idx / 9;
    int c = rem % C_;
    int o = rem / C_;
    int og = o / 9, oo = o % 9;
    wt[((size_t)og * C_ + c) * WSTR + oo * 9 + tap] = w[idx];
}

// ---------------- K1: per-(b,c) spatial mean (SGE gap) ----------------
__global__ __launch_bounds__(256) void gap_kernel(const float* __restrict__ x,
                                                  float* __restrict__ gap) {
    int bc = blockIdx.x;                     // 0..2047
    const float4* p = (const float4*)(x + (size_t)bc * HW);
    float sum = 0.f;
    for (int idx = threadIdx.x; idx < HW / 4; idx += 256) {
        float4 v = p[idx];
        sum += v.x + v.y + v.z + v.w;
    }
    #pragma unroll
    for (int m = 32; m >= 1; m >>= 1) sum += __shfl_xor(sum, m, 64);
    __shared__ float red[4];
    int wid = threadIdx.x >> 6;
    if ((threadIdx.x & 63) == 0) red[wid] = sum;
    __syncthreads();
    if (threadIdx.x == 0)
        gap[bc] = (red[0] + red[1] + red[2] + red[3]) * (1.f / (float)HW);
}

// ---------------- K2: xn = sum_ch xg*gap, + per-(b,g) sum/sumsq ----------------
__global__ __launch_bounds__(256) void xn_kernel(const float* __restrict__ x,
                                                 const float* __restrict__ gap,
                                                 float* __restrict__ xng,
                                                 float* __restrict__ sge_stats) {
    int blk = blockIdx.x;                    // B_*G_*36 = 2304
    int bg = blk / 36, chunk = blk % 36;
    int b = bg >> 3, g = bg & 7;
    int p = chunk * 256 + threadIdx.x;
    const float* xbase = x + ((size_t)b * C_ + g * CPG) * HW + p;
    const float* gp = gap + b * C_ + g * CPG;
    float v = 0.f;
    #pragma unroll
    for (int ch = 0; ch < CPG; ch++) v += xbase[(size_t)ch * HW] * gp[ch];
    xng[(size_t)bg * HW + p] = v;
    float v1 = v, v2 = v * v;
    #pragma unroll
    for (int m = 32; m >= 1; m >>= 1) {
        v1 += __shfl_xor(v1, m, 64);
        v2 += __shfl_xor(v2, m, 64);
    }
    __shared__ float r1[4], r2[4];
    int wid = threadIdx.x >> 6;
    if ((threadIdx.x & 63) == 0) { r1[wid] = v1; r2[wid] = v2; }
    __syncthreads();
    if (threadIdx.x == 0) {
        atomicAdd(&sge_stats[bg * 2 + 0], r1[0] + r1[1] + r1[2] + r1[3]);
        atomicAdd(&sge_stats[bg * 2 + 1], r2[0] + r2[1] + r2[2] + r2[3]);
    }
}

// ---------------- K3: gate = sigmoid(normalized(xn)*w + b), in place ----------------
__global__ __launch_bounds__(256) void gate_kernel(float* __restrict__ xng,
                                                   const float* __restrict__ stats,
                                                   const float* __restrict__ sw,
                                                   const float* __restrict__ sb) {
    int idx = blockIdx.x * 256 + threadIdx.x;    // exactly 589824
    int bg = idx / HW;
    int g = bg & 7;
    float sum = stats[bg * 2], sumsq = stats[bg * 2 + 1];
    float mean = sum * (1.f / (float)HW);
    float var = (sumsq - sum * mean) * (1.f / (float)(HW - 1));
    var = fmaxf(var, 0.f);
    float sd = sqrtf(var) + 1e-5f;
    float tv = (xng[idx] - mean) / sd * sw[g] + sb[g];
    xng[idx] = 1.f / (1.f + expf(-tv));
}

// ---------------- K4: 3x3 conv (reflect pad) + BN batch-stat accumulation ----------------
// v5: VGPR weight pipeline.
//  - R3 stall: 81 weights/cc via s_load; SGPR file (~102) can't hold 2 cc's worth ->
//    2-3 exposed ~200cy lgkm waits per 486cy FMA block -> VALUBusy ~49%.
//  - fix: og left divergent-typed (no readfirstlane) -> weight loads go VMEM->VGPR
//    (uniform addr coalesces to 1 line); explicit one-channel-ahead prefetch with
//    wA/wB float4[21] rotation (static indices only). 486cy FMA hides ~200cy L2.
//  - CCH 8->4 (fewer staging regs), launch_bounds(256,1) for the ~230-VGPR peak.
#define CCH 4
#define XS_ELEMS (CCH * 4 * 98)   // 1568 floats = 6272 B per buffer

#define WG(A, i) ((((i)&3)==0) ? A[(i)>>2].x : (((i)&3)==1) ? A[(i)>>2].y : \
                  (((i)&3)==2) ? A[(i)>>2].z : A[(i)>>2].w)

#define BODY(CCI, WU, WF) do {                                                   \
    const float4* wnp_ = (const float4*)(wtp + (size_t)(c0 + (CCI) + 1) * WSTR); \
    _Pragma("unroll")                                                            \
    for (int q = 0; q < 21; q++) WF[q] = wnp_[q];                                \
    float xv[3][5];                                                              \
    const float* xr_ = bufA + (CCI) * 392;                                       \
    _Pragma("unroll")                                                            \
    for (int r = 0; r < 3; r++)                                                  \
        _Pragma("unroll")                                                        \
        for (int d = 0; d < 5; d++)                                              \
            xv[r][d] = xr_[(row + r) * 98 + 3 * k + d];                          \
    _Pragma("unroll")                                                            \
    for (int oo = 0; oo < 9; oo++) {                                             \
        float w0 = WG(WU, oo*9+0), w1 = WG(WU, oo*9+1), w2 = WG(WU, oo*9+2);     \
        float w3 = WG(WU, oo*9+3), w4 = WG(WU, oo*9+4), w5 = WG(WU, oo*9+5);     \
        float w6 = WG(WU, oo*9+6), w7 = WG(WU, oo*9+7), w8 = WG(WU, oo*9+8);     \
        _Pragma("unroll")                                                        \
        for (int px = 0; px < 3; px++) {                                         \
            acc[oo][px] += xv[0][px] * w0 + xv[0][px+1] * w1 + xv[0][px+2] * w2  \
                         + xv[1][px] * w3 + xv[1][px+1] * w4 + xv[1][px+2] * w5  \
                         + xv[2][px] * w6 + xv[2][px+1] * w7 + xv[2][px+2] * w8; \
        }                                                                        \
    }                                                                            \
} while (0)

__global__ __launch_bounds__(256, 1) void conv_kernel(const float* __restrict__ x,
                                                      const float* __restrict__ wt,
                                                      float* __restrict__ s,
                                                      float* __restrict__ bn_stats) {
    int phys = blockIdx.x;                       // 768 blocks
    int blk = (phys & 7) * 96 + (phys >> 3);     // bijective XCD chunking (768 = 8*96)
    int ogsel = blk & 1;
    int np = blk >> 1;                           // 0..383
    int n = np / 48, pair = np % 48;
    int i0 = pair * 2;
    int t = threadIdx.x;
    int wid = t >> 6;                            // wave 0..3
    int lane = t & 63;
    int row = lane >> 5;                         // output row within pair: 0/1
    int k = lane & 31;                           // col group: output cols 3k..3k+2
    int og = ogsel * 4 + wid;                    // divergent-typed -> VGPR weight path

    __shared__ float xs0[XS_ELEMS];
    __shared__ float xs1[XS_ELEMS];

    // ---- precompute per-thread staging source offsets (rel. to xb + c0*HW) ----
    int off[7];
    #pragma unroll
    for (int it = 0; it < 7; it++) {
        if (it == 6 && t >= 32) { off[it] = 0; continue; }
        int gidx = it * 256 + t;                 // 0..1567
        int cc = gidx / 392;
        int rem = gidx - cc * 392;
        int r = rem / 98;
        int col = rem - r * 98;
        int gcol = col - 1;
        if (gcol < 0) gcol = 1; else if (gcol > 95) gcol = 94;
        int ri = i0 - 1 + r;                     // reflected input row
        if (ri < 0) ri = 1; else if (ri > 95) ri = 94;
        off[it] = cc * HW + ri * W_ + gcol;
    }

    float acc[9][3];
    #pragma unroll
    for (int a = 0; a < 9; a++)
        #pragma unroll
        for (int b2 = 0; b2 < 3; b2++) acc[a][b2] = 0.f;

    const float* xb = x + (size_t)n * C_ * HW;
    const float* wtp = wt + (size_t)og * (C_ * WSTR);   // per-thread (wave-uniform value)
    float* bufA = xs0;                           // buffer being computed
    float* bufB = xs1;                           // buffer being filled

    float4 wA[21], wB[21];

    // ---- prologue: stage chunk 0 into xs0, load weights for c=0 into wA ----
    {
        float ld[7];
        #pragma unroll
        for (int it = 0; it < 6; it++) ld[it] = xb[off[it]];
        if (t < 32) ld[6] = xb[off[6]];
        #pragma unroll
        for (int it = 0; it < 6; it++) xs0[it * 256 + t] = ld[it];
        if (t < 32) xs0[6 * 256 + t] = ld[6];
        const float4* wp0 = (const float4*)wtp;
        #pragma unroll
        for (int q = 0; q < 21; q++) wA[q] = wp0[q];
    }
    __syncthreads();

    for (int c0 = 0; c0 < C_; c0 += CCH) {
        // phase A: issue next chunk's x loads (latency hides under compute)
        float ld[7];
        const bool have_next = (c0 + CCH < C_);
        if (have_next) {
            const float* src = xb + (size_t)(c0 + CCH) * HW;
            #pragma unroll
            for (int it = 0; it < 6; it++) ld[it] = src[off[it]];
            if (t < 32) ld[6] = src[off[6]];
        }
        // phase B: 4 channels, weight buffers rotate; each body prefetches c+1
        BODY(0, wA, wB);
        BODY(1, wB, wA);
        BODY(2, wA, wB);
        BODY(3, wB, wA);       // fills wA with next chunk's first channel
        // phase C: write staged regs into bufB, one barrier per chunk
        if (have_next) {
            #pragma unroll
            for (int it = 0; it < 6; it++) bufB[it * 256 + t] = ld[it];
            if (t < 32) bufB[6 * 256 + t] = ld[6];
        }
        __syncthreads();
        float* tmp = bufA; bufA = bufB; bufB = tmp;
    }

    // write s (lane k writes cols 3k..3k+2, contiguous per wave) + per-channel stats
    int i = i0 + row;
    #pragma unroll
    for (int oo = 0; oo < 9; oo++) {
        int o = og * 9 + oo;
        float* sp = s + ((size_t)(n * O_ + o) * H_ + i) * W_ + 3 * k;
        sp[0] = acc[oo][0]; sp[1] = acc[oo][1]; sp[2] = acc[oo][2];
        float v1 = acc[oo][0] + acc[oo][1] + acc[oo][2];
        float v2 = acc[oo][0] * acc[oo][0] + acc[oo][1] * acc[oo][1] + acc[oo][2] * acc[oo][2];
        #pragma unroll
        for (int m = 32; m >= 1; m >>= 1) {
            v1 += __shfl_xor(v1, m, 64);
            v2 += __shfl_xor(v2, m, 64);
        }
        if (lane == 0) {
            atomicAdd(&bn_stats[o * 2 + 0], v1);
            atomicAdd(&bn_stats[o * 2 + 1], v2);
        }
    }
}

// ---------------- K6: BN + softmax(72) + 9-tap gather * gate * sigma ----------------
__global__ __launch_bounds__(256, 2) void out_kernel(const float* __restrict__ x,
                                                     const float* __restrict__ s,
                                                     const float* __restrict__ bn_stats,
                                                     const float* __restrict__ gamma,
                                                     const float* __restrict__ beta,
                                                     const float* __restrict__ gate,
                                                     float* __restrict__ out) {
    int blk = blockIdx.x;                    // 768
    int n = blk / H_, i = blk % H_;
    int t = threadIdx.x;
    __shared__ float sg[O_][W_];             // exp(bn(s)) for this row
    __shared__ float rden[W_];
    __shared__ float gt[G_][3][98];          // gate at reflected tap coords

    int r0 = i - 1; if (r0 < 0) r0 = 1;
    int r2 = i + 1; if (r2 > 95) r2 = 94;
    int rows[3] = { r0, i, r2 };

    for (int idx = t; idx < G_ * 3 * 98; idx += 256) {
        int g = idx / (3 * 98), rem = idx % (3 * 98);
        int r = rem / 98, col = rem % 98;
        int gcol = col - 1;
        if (gcol < 0) gcol = 1; else if (gcol > 95) gcol = 94;
        gt[g][r][col] = gate[((size_t)(n * G_ + g)) * HW + rows[r] * W_ + gcol];
    }
    const float inv = 1.f / (float)NPX;
    for (int idx = t; idx < O_ * W_; idx += 256) {
        int o = idx / W_, j = idx % W_;
        float sum = bn_stats[o * 2], ssq = bn_stats[o * 2 + 1];
        float mean = sum * inv;
        float var = ssq * inv - mean * mean;
        float sc = rsqrtf(var + 1e-5f) * gamma[o];
        float val = (s[((size_t)(n * O_ + o) * H_ + i) * W_ + j] - mean) * sc + beta[o];
        sg[o][j] = expf(val);
    }
    __syncthreads();
    if (t < W_) {
        float d = 0.f;
        #pragma unroll
        for (int o = 0; o < O_; o++) d += sg[o][t];
        rden[t] = 1.f / d;
    }
    __syncthreads();

    const float* xb = x + (size_t)n * C_ * HW;
    for (int idx = t; idx < C_ * W_; idx += 256) {
        int c = idx / W_, j = idx % W_;
        int g = c >> 5;
        const float* xc = xb + (size_t)c * HW;
        int jm1 = j - 1; if (jm1 < 0) jm1 = 1;
        int jp1 = j + 1; if (jp1 > 95) jp1 = 94;
        int cols[3] = { jm1, j, jp1 };
        float acc = 0.f;
        #pragma unroll
        for (int r = 0; r < 3; r++) {
            const float* xr = xc + rows[r] * W_;
            #pragma unroll
            for (int dx = 0; dx < 3; dx++) {
                float xv = xr[cols[dx]];
                float gv = gt[g][r][j + dx];
                float sv = sg[g * 9 + r * 3 + dx][j];
                acc += xv * gv * sv;
            }
        }
        out[((size_t)(n * C_ + c) * H_ + i) * W_ + j] = acc * rden[j];
    }
}

extern "C" void kernel_launch(void* const* d_in, const int* in_sizes, int n_in,
                              void* d_out, int out_size, void* d_ws, size_t ws_size,
                              hipStream_t stream) {
    const float* x      = (const float*)d_in[0];
    const float* sge_w  = (const float*)d_in[1];
    const float* sge_b  = (const float*)d_in[2];
    const float* conv_w = (const float*)d_in[3];
    const float* gamma  = (const float*)d_in[4];
    const float* beta   = (const float*)d_in[5];
    float* out = (float*)d_out;
    float* ws = (float*)d_ws;

    // workspace layout (floats) — wt placed BEFORE s so the final harmless
    // one-channel prefetch overread (og=7, c=256) lands inside s, in-bounds.
    float* sge_stats = ws;            // 128    (sum,sumsq per b*g)
    float* bn_stats  = ws + 128;      // 144    (sum,sumsq per o)
    float* gap       = ws + 272;      // 2048
    float* xng       = ws + 2320;     // 589824 (xn, overwritten in-place by gate)
    float* wt        = ws + 592144;   // 172032 transposed weights (8*256*84)
    float* s         = ws + 764176;   // 5308416 conv output
    // total ~24.3 MB

    hipMemsetAsync(d_ws, 0, 272 * sizeof(float), stream);  // zero stats each call
    hipLaunchKernelGGL(wprep_kernel, dim3(648),         dim3(256), 0, stream, conv_w, wt);
    hipLaunchKernelGGL(gap_kernel,   dim3(B_ * C_),     dim3(256), 0, stream, x, gap);
    hipLaunchKernelGGL(xn_kernel,    dim3(B_ * G_ * 36),dim3(256), 0, stream, x, gap, xng, sge_stats);
    hipLaunchKernelGGL(gate_kernel,  dim3(B_ * G_ * 36),dim3(256), 0, stream, xng, sge_stats, sge_w, sge_b);
    hipLaunchKernelGGL(conv_kernel,  dim3(768),         dim3(256), 0, stream, x, wt, s, bn_stats);
    hipLaunchKernelGGL(out_kernel,   dim3(B_ * H_),     dim3(256), 0, stream, x, s, bn_stats, gamma, beta, xng, out);
}

// Round 5
// 1599.847 us; speedup vs baseline: 1.7615x; 1.7615x over previous
//
#include <hip/hip_runtime.h>
#include <hip/hip_bf16.h>

// Problem constants
#define B_  8
#define C_  256
#define H_  96
#define W_  96
#define G_  8
#define CPG 32          // C_/G_
#define KK  9           // 3x3 taps
#define O_  72          // G_*KK conv out channels
#define HW  9216        // H_*W_
#define NPX 73728       // B_*HW (BN population per channel)
#define WSTR 108        // wT per-(og,c) stride: 9 oo-groups x 12 floats (48B each, 16B-aligned)

// ---------------- K0: weight transpose  w[o][c][tap] -> wT[og][c][oo*12+tap] ----------------
__global__ __launch_bounds__(256) void wprep_kernel(const float* __restrict__ w,
                                                    float* __restrict__ wt) {
    int idx = blockIdx.x * 256 + threadIdx.x;        // O_*C_*12 = 221184
    if (idx >= O_ * C_ * 12) return;
    int tap = idx % 12;
    int rem = idx / 12;
    int c = rem % C_;
    int o = rem / C_;
    int og = o / 9, oo = o % 9;
    float v = (tap < 9) ? w[((size_t)o * C_ + c) * 9 + tap] : 0.f;
    wt[((size_t)og * C_ + c) * WSTR + oo * 12 + tap] = v;
}

// ---------------- K1: per-(b,c) spatial mean (SGE gap) ----------------
__global__ __launch_bounds__(256) void gap_kernel(const float* __restrict__ x,
                                                  float* __restrict__ gap) {
    int bc = blockIdx.x;                     // 0..2047
    const float4* p = (const float4*)(x + (size_t)bc * HW);
    float sum = 0.f;
    for (int idx = threadIdx.x; idx < HW / 4; idx += 256) {
        float4 v = p[idx];
        sum += v.x + v.y + v.z + v.w;
    }
    #pragma unroll
    for (int m = 32; m >= 1; m >>= 1) sum += __shfl_xor(sum, m, 64);
    __shared__ float red[4];
    int wid = threadIdx.x >> 6;
    if ((threadIdx.x & 63) == 0) red[wid] = sum;
    __syncthreads();
    if (threadIdx.x == 0)
        gap[bc] = (red[0] + red[1] + red[2] + red[3]) * (1.f / (float)HW);
}

// ---------------- K2: xn = sum_ch xg*gap, + per-(b,g) sum/sumsq ----------------
__global__ __launch_bounds__(256) void xn_kernel(const float* __restrict__ x,
                                                 const float* __restrict__ gap,
                                                 float* __restrict__ xng,
                                                 float* __restrict__ sge_stats) {
    int blk = blockIdx.x;                    // B_*G_*36 = 2304
    int bg = blk / 36, chunk = blk % 36;
    int b = bg >> 3, g = bg & 7;
    int p = chunk * 256 + threadIdx.x;
    const float* xbase = x + ((size_t)b * C_ + g * CPG) * HW + p;
    const float* gp = gap + b * C_ + g * CPG;
    float v = 0.f;
    #pragma unroll
    for (int ch = 0; ch < CPG; ch++) v += xbase[(size_t)ch * HW] * gp[ch];
    xng[(size_t)bg * HW + p] = v;
    float v1 = v, v2 = v * v;
    #pragma unroll
    for (int m = 32; m >= 1; m >>= 1) {
        v1 += __shfl_xor(v1, m, 64);
        v2 += __shfl_xor(v2, m, 64);
    }
    __shared__ float r1[4], r2[4];
    int wid = threadIdx.x >> 6;
    if ((threadIdx.x & 63) == 0) { r1[wid] = v1; r2[wid] = v2; }
    __syncthreads();
    if (threadIdx.x == 0) {
        atomicAdd(&sge_stats[bg * 2 + 0], r1[0] + r1[1] + r1[2] + r1[3]);
        atomicAdd(&sge_stats[bg * 2 + 1], r2[0] + r2[1] + r2[2] + r2[3]);
    }
}

// ---------------- K3: gate = sigmoid(normalized(xn)*w + b), in place ----------------
__global__ __launch_bounds__(256) void gate_kernel(float* __restrict__ xng,
                                                   const float* __restrict__ stats,
                                                   const float* __restrict__ sw,
                                                   const float* __restrict__ sb) {
    int idx = blockIdx.x * 256 + threadIdx.x;    // exactly 589824
    int bg = idx / HW;
    int g = bg & 7;
    float sum = stats[bg * 2], sumsq = stats[bg * 2 + 1];
    float mean = sum * (1.f / (float)HW);
    float var = (sumsq - sum * mean) * (1.f / (float)(HW - 1));
    var = fmaxf(var, 0.f);
    float sd = sqrtf(var) + 1e-5f;
    float tv = (xng[idx] - mean) / sd * sw[g] + sb[g];
    xng[idx] = 1.f / (1.f + expf(-tv));
}

// ---------------- K4: 3x3 conv (reflect pad) + BN batch-stat accumulation ----------------
// v6: 12-float-granular VGPR weight pipeline (R4's idea, register-sized right).
//  - wq[4][3] float4 = 48 VGPRs (R4's 168 spilled). Body g: consume wq[g&3] (27 FMA),
//    then refill the same slot with tap-group g+4 (3x dwordx4, uniform addr -> 1 line).
//    36 groups/chunk % 4 == 0 -> slot indices compile-time static across the c0 loop.
//  - ~162cy issue->reuse distance; residue hidden by 4 waves/SIMD if VGPR <= 128.
//  - everything else = R3's proven structure (x dbuf staging, precomputed offsets).
#define CCH 4
#define XS_ELEMS (CCH * 4 * 98)   // 1568 floats = 6272 B per buffer

#define OBODY(CCI, OO) do {                                                      \
    enum { g_ = (CCI)*9 + (OO), buf_ = g_ & 3, gp_ = g_ + 4,                     \
           ccip_ = gp_ / 9, oop_ = gp_ % 9 };                                    \
    float w0 = wq[buf_][0].x, w1 = wq[buf_][0].y, w2 = wq[buf_][0].z;            \
    float w3 = wq[buf_][0].w, w4 = wq[buf_][1].x, w5 = wq[buf_][1].y;            \
    float w6 = wq[buf_][1].z, w7 = wq[buf_][1].w, w8 = wq[buf_][2].x;            \
    _Pragma("unroll")                                                            \
    for (int px = 0; px < 3; px++) {                                             \
        acc[OO][px] += xv[0][px] * w0 + xv[0][px+1] * w1 + xv[0][px+2] * w2      \
                     + xv[1][px] * w3 + xv[1][px+1] * w4 + xv[1][px+2] * w5      \
                     + xv[2][px] * w6 + xv[2][px+1] * w7 + xv[2][px+2] * w8;     \
    }                                                                            \
    { const float4* wp_ = (const float4*)(wtp + (size_t)(c0 + ccip_) * WSTR + oop_ * 12); \
      wq[buf_][0] = wp_[0]; wq[buf_][1] = wp_[1]; wq[buf_][2] = wp_[2]; }        \
} while (0)

#define CCBLOCK(CCI) do {                                                        \
    float xv[3][5];                                                              \
    {   const float* xr_ = bufA + (CCI) * 392;                                   \
        _Pragma("unroll")                                                        \
        for (int r = 0; r < 3; r++)                                              \
            _Pragma("unroll")                                                    \
            for (int d = 0; d < 5; d++)                                          \
                xv[r][d] = xr_[(row + r) * 98 + 3 * k + d]; }                    \
    OBODY(CCI,0); OBODY(CCI,1); OBODY(CCI,2); OBODY(CCI,3); OBODY(CCI,4);        \
    OBODY(CCI,5); OBODY(CCI,6); OBODY(CCI,7); OBODY(CCI,8);                      \
} while (0)

#define WLOADP(BUF, OO) do {                                                     \
    const float4* wp_ = (const float4*)(wtp + (OO) * 12);                        \
    wq[BUF][0] = wp_[0]; wq[BUF][1] = wp_[1]; wq[BUF][2] = wp_[2]; } while (0)

__global__ __launch_bounds__(256, 1) void conv_kernel(const float* __restrict__ x,
                                                      const float* __restrict__ wt,
                                                      float* __restrict__ s,
                                                      float* __restrict__ bn_stats) {
    int phys = blockIdx.x;                       // 768 blocks
    int blk = (phys & 7) * 96 + (phys >> 3);     // bijective XCD chunking (768 = 8*96)
    int ogsel = blk & 1;
    int np = blk >> 1;                           // 0..383
    int n = np / 48, pair = np % 48;
    int i0 = pair * 2;
    int t = threadIdx.x;
    int wid = t >> 6;                            // wave 0..3
    int lane = t & 63;
    int row = lane >> 5;                         // output row within pair: 0/1
    int k = lane & 31;                           // col group: output cols 3k..3k+2
    int og = ogsel * 4 + wid;                    // divergent-typed -> VMEM weight path

    __shared__ float xs0[XS_ELEMS];
    __shared__ float xs1[XS_ELEMS];

    // ---- precompute per-thread staging source offsets (rel. to xb + c0*HW) ----
    int off[7];
    #pragma unroll
    for (int it = 0; it < 7; it++) {
        if (it == 6 && t >= 32) { off[it] = 0; continue; }
        int gidx = it * 256 + t;                 // 0..1567
        int cc = gidx / 392;
        int rem = gidx - cc * 392;
        int r = rem / 98;
        int col = rem - r * 98;
        int gcol = col - 1;
        if (gcol < 0) gcol = 1; else if (gcol > 95) gcol = 94;
        int ri = i0 - 1 + r;                     // reflected input row
        if (ri < 0) ri = 1; else if (ri > 95) ri = 94;
        off[it] = cc * HW + ri * W_ + gcol;
    }

    float acc[9][3];
    #pragma unroll
    for (int a = 0; a < 9; a++)
        #pragma unroll
        for (int b2 = 0; b2 < 3; b2++) acc[a][b2] = 0.f;

    const float* xb = x + (size_t)n * C_ * HW;
    const float* wtp = wt + (size_t)og * (C_ * WSTR);   // per-thread (wave-uniform value)
    float* bufA = xs0;                           // buffer being computed
    float* bufB = xs1;                           // buffer being filled

    float4 wq[4][3];                             // 4-deep weight rotation (48 VGPRs)

    // ---- prologue: stage chunk 0 into xs0, prime weight groups 0..3 ----
    {
        float ld[7];
        #pragma unroll
        for (int it = 0; it < 6; it++) ld[it] = xb[off[it]];
        if (t < 32) ld[6] = xb[off[6]];
        #pragma unroll
        for (int it = 0; it < 6; it++) xs0[it * 256 + t] = ld[it];
        if (t < 32) xs0[6 * 256 + t] = ld[6];
        WLOADP(0, 0); WLOADP(1, 1); WLOADP(2, 2); WLOADP(3, 3);
    }
    __syncthreads();

    for (int c0 = 0; c0 < C_; c0 += CCH) {
        // phase A: issue next chunk's x loads (latency hides under compute)
        float ld[7];
        const bool have_next = (c0 + CCH < C_);
        if (have_next) {
            const float* src = xb + (size_t)(c0 + CCH) * HW;
            #pragma unroll
            for (int it = 0; it < 6; it++) ld[it] = src[off[it]];
            if (t < 32) ld[6] = src[off[6]];
        }
        // phase B: 4 channels x 9 tap-groups; each body refills its wq slot (+4 ahead)
        CCBLOCK(0); CCBLOCK(1); CCBLOCK(2); CCBLOCK(3);
        // phase C: write staged regs into bufB, one barrier per chunk
        if (have_next) {
            #pragma unroll
            for (int it = 0; it < 6; it++) bufB[it * 256 + t] = ld[it];
            if (t < 32) bufB[6 * 256 + t] = ld[6];
        }
        __syncthreads();
        float* tmp = bufA; bufA = bufB; bufB = tmp;
    }

    // write s (lane k writes cols 3k..3k+2, contiguous per wave) + per-channel stats
    int i = i0 + row;
    #pragma unroll
    for (int oo = 0; oo < 9; oo++) {
        int o = og * 9 + oo;
        float* sp = s + ((size_t)(n * O_ + o) * H_ + i) * W_ + 3 * k;
        sp[0] = acc[oo][0]; sp[1] = acc[oo][1]; sp[2] = acc[oo][2];
        float v1 = acc[oo][0] + acc[oo][1] + acc[oo][2];
        float v2 = acc[oo][0] * acc[oo][0] + acc[oo][1] * acc[oo][1] + acc[oo][2] * acc[oo][2];
        #pragma unroll
        for (int m = 32; m >= 1; m >>= 1) {
            v1 += __shfl_xor(v1, m, 64);
            v2 += __shfl_xor(v2, m, 64);
        }
        if (lane == 0) {
            atomicAdd(&bn_stats[o * 2 + 0], v1);
            atomicAdd(&bn_stats[o * 2 + 1], v2);
        }
    }
}

// ---------------- K6: BN + softmax(72) + 9-tap gather * gate * sigma ----------------
__global__ __launch_bounds__(256, 2) void out_kernel(const float* __restrict__ x,
                                                     const float* __restrict__ s,
                                                     const float* __restrict__ bn_stats,
                                                     const float* __restrict__ gamma,
                                                     const float* __restrict__ beta,
                                                     const float* __restrict__ gate,
                                                     float* __restrict__ out) {
    int blk = blockIdx.x;                    // 768
    int n = blk / H_, i = blk % H_;
    int t = threadIdx.x;
    __shared__ float sg[O_][W_];             // exp(bn(s)) for this row
    __shared__ float rden[W_];
    __shared__ float gt[G_][3][98];          // gate at reflected tap coords

    int r0 = i - 1; if (r0 < 0) r0 = 1;
    int r2 = i + 1; if (r2 > 95) r2 = 94;
    int rows[3] = { r0, i, r2 };

    for (int idx = t; idx < G_ * 3 * 98; idx += 256) {
        int g = idx / (3 * 98), rem = idx % (3 * 98);
        int r = rem / 98, col = rem % 98;
        int gcol = col - 1;
        if (gcol < 0) gcol = 1; else if (gcol > 95) gcol = 94;
        gt[g][r][col] = gate[((size_t)(n * G_ + g)) * HW + rows[r] * W_ + gcol];
    }
    const float inv = 1.f / (float)NPX;
    for (int idx = t; idx < O_ * W_; idx += 256) {
        int o = idx / W_, j = idx % W_;
        float sum = bn_stats[o * 2], ssq = bn_stats[o * 2 + 1];
        float mean = sum * inv;
        float var = ssq * inv - mean * mean;
        float sc = rsqrtf(var + 1e-5f) * gamma[o];
        float val = (s[((size_t)(n * O_ + o) * H_ + i) * W_ + j] - mean) * sc + beta[o];
        sg[o][j] = expf(val);
    }
    __syncthreads();
    if (t < W_) {
        float d = 0.f;
        #pragma unroll
        for (int o = 0; o < O_; o++) d += sg[o][t];
        rden[t] = 1.f / d;
    }
    __syncthreads();

    const float* xb = x + (size_t)n * C_ * HW;
    for (int idx = t; idx < C_ * W_; idx += 256) {
        int c = idx / W_, j = idx % W_;
        int g = c >> 5;
        const float* xc = xb + (size_t)c * HW;
        int jm1 = j - 1; if (jm1 < 0) jm1 = 1;
        int jp1 = j + 1; if (jp1 > 95) jp1 = 94;
        int cols[3] = { jm1, j, jp1 };
        float acc = 0.f;
        #pragma unroll
        for (int r = 0; r < 3; r++) {
            const float* xr = xc + rows[r] * W_;
            #pragma unroll
            for (int dx = 0; dx < 3; dx++) {
                float xv = xr[cols[dx]];
                float gv = gt[g][r][j + dx];
                float sv = sg[g * 9 + r * 3 + dx][j];
                acc += xv * gv * sv;
            }
        }
        out[((size_t)(n * C_ + c) * H_ + i) * W_ + j] = acc * rden[j];
    }
}

extern "C" void kernel_launch(void* const* d_in, const int* in_sizes, int n_in,
                              void* d_out, int out_size, void* d_ws, size_t ws_size,
                              hipStream_t stream) {
    const float* x      = (const float*)d_in[0];
    const float* sge_w  = (const float*)d_in[1];
    const float* sge_b  = (const float*)d_in[2];
    const float* conv_w = (const float*)d_in[3];
    const float* gamma  = (const float*)d_in[4];
    const float* beta   = (const float*)d_in[5];
    float* out = (float*)d_out;
    float* ws = (float*)d_ws;

    // workspace layout (floats) — wt placed BEFORE s so the final harmless
    // one-group prefetch overread (og=7, c=256) lands inside s, in-bounds.
    float* sge_stats = ws;            // 128    (sum,sumsq per b*g)
    float* bn_stats  = ws + 128;      // 144    (sum,sumsq per o)
    float* gap       = ws + 272;      // 2048
    float* xng       = ws + 2320;     // 589824 (xn, overwritten in-place by gate)
    float* wt        = ws + 592144;   // 221184 transposed weights (8*256*108)
    float* s         = ws + 813328;   // 5308416 conv output
    // total ~24.5 MB

    hipMemsetAsync(d_ws, 0, 272 * sizeof(float), stream);  // zero stats each call
    hipLaunchKernelGGL(wprep_kernel, dim3(864),         dim3(256), 0, stream, conv_w, wt);
    hipLaunchKernelGGL(gap_kernel,   dim3(B_ * C_),     dim3(256), 0, stream, x, gap);
    hipLaunchKernelGGL(xn_kernel,    dim3(B_ * G_ * 36),dim3(256), 0, stream, x, gap, xng, sge_stats);
    hipLaunchKernelGGL(gate_kernel,  dim3(B_ * G_ * 36),dim3(256), 0, stream, xng, sge_stats, sge_w, sge_b);
    hipLaunchKernelGGL(conv_kernel,  dim3(768),         dim3(256), 0, stream, x, wt, s, bn_stats);
    hipLaunchKernelGGL(out_kernel,   dim3(B_ * H_),     dim3(256), 0, stream, x, s, bn_stats, gamma, beta, xng, out);
}

// Round 6
// 624.586 us; speedup vs baseline: 4.5119x; 2.5615x over previous
//
#include <hip/hip_runtime.h>
#include <hip/hip_bf16.h>

// Problem constants
#define B_  8
#define C_  256
#define H_  96
#define W_  96
#define G_  8
#define CPG 32          // C_/G_
#define KK  9           // 3x3 taps
#define O_  72          // G_*KK conv out channels
#define HW  9216        // H_*W_
#define NPX 73728       // B_*HW (BN population per channel)
#define WSTR 84         // wT per-(og,c) stride: 81 used, padded to 84 (336B, 16B-aligned)

// ---------------- K0: weight transpose  w[o][c][tap] -> wT[og][c][oo*9+tap] ----------------
__global__ __launch_bounds__(256) void wprep_kernel(const float* __restrict__ w,
                                                    float* __restrict__ wt) {
    int idx = blockIdx.x * 256 + threadIdx.x;        // O_*C_*KK = 165888
    if (idx >= O_ * C_ * KK) return;
    int tap = idx % 9;
    int rem = idx / 9;
    int c = rem % C_;
    int o = rem / C_;
    int og = o / 9, oo = o % 9;
    wt[((size_t)og * C_ + c) * WSTR + oo * 9 + tap] = w[idx];
}

// ---------------- K1: per-(b,c) spatial mean (SGE gap) ----------------
__global__ __launch_bounds__(256) void gap_kernel(const float* __restrict__ x,
                                                  float* __restrict__ gap) {
    int bc = blockIdx.x;                     // 0..2047
    const float4* p = (const float4*)(x + (size_t)bc * HW);
    float sum = 0.f;
    for (int idx = threadIdx.x; idx < HW / 4; idx += 256) {
        float4 v = p[idx];
        sum += v.x + v.y + v.z + v.w;
    }
    #pragma unroll
    for (int m = 32; m >= 1; m >>= 1) sum += __shfl_xor(sum, m, 64);
    __shared__ float red[4];
    int wid = threadIdx.x >> 6;
    if ((threadIdx.x & 63) == 0) red[wid] = sum;
    __syncthreads();
    if (threadIdx.x == 0)
        gap[bc] = (red[0] + red[1] + red[2] + red[3]) * (1.f / (float)HW);
}

// ---------------- K2: xn = sum_ch xg*gap, + per-(b,g) sum/sumsq ----------------
__global__ __launch_bounds__(256) void xn_kernel(const float* __restrict__ x,
                                                 const float* __restrict__ gap,
                                                 float* __restrict__ xng,
                                                 float* __restrict__ sge_stats) {
    int blk = blockIdx.x;                    // B_*G_*36 = 2304
    int bg = blk / 36, chunk = blk % 36;
    int b = bg >> 3, g = bg & 7;
    int p = chunk * 256 + threadIdx.x;
    const float* xbase = x + ((size_t)b * C_ + g * CPG) * HW + p;
    const float* gp = gap + b * C_ + g * CPG;
    float v = 0.f;
    #pragma unroll
    for (int ch = 0; ch < CPG; ch++) v += xbase[(size_t)ch * HW] * gp[ch];
    xng[(size_t)bg * HW + p] = v;
    float v1 = v, v2 = v * v;
    #pragma unroll
    for (int m = 32; m >= 1; m >>= 1) {
        v1 += __shfl_xor(v1, m, 64);
        v2 += __shfl_xor(v2, m, 64);
    }
    __shared__ float r1[4], r2[4];
    int wid = threadIdx.x >> 6;
    if ((threadIdx.x & 63) == 0) { r1[wid] = v1; r2[wid] = v2; }
    __syncthreads();
    if (threadIdx.x == 0) {
        atomicAdd(&sge_stats[bg * 2 + 0], r1[0] + r1[1] + r1[2] + r1[3]);
        atomicAdd(&sge_stats[bg * 2 + 1], r2[0] + r2[1] + r2[2] + r2[3]);
    }
}

// ---------------- K3: gate = sigmoid(normalized(xn)*w + b), in place ----------------
__global__ __launch_bounds__(256) void gate_kernel(float* __restrict__ xng,
                                                   const float* __restrict__ stats,
                                                   const float* __restrict__ sw,
                                                   const float* __restrict__ sb) {
    int idx = blockIdx.x * 256 + threadIdx.x;    // exactly 589824
    int bg = idx / HW;
    int g = bg & 7;
    float sum = stats[bg * 2], sumsq = stats[bg * 2 + 1];
    float mean = sum * (1.f / (float)HW);
    float var = (sumsq - sum * mean) * (1.f / (float)(HW - 1));
    var = fmaxf(var, 0.f);
    float sd = sqrtf(var) + 1e-5f;
    float tv = (xng[idx] - mean) / sd * sw[g] + sb[g];
    xng[idx] = 1.f / (1.f + expf(-tv));
}

// ---------------- K4: 3x3 conv (reflect pad), channel-split, atomic accumulate ----------------
// v7 = R3's proven 480µs structure (s_load weights, dbuf staging, VGPR 60) + TLP fix:
//  - R3 stall: all block waves barrier-locked, stall in unison at per-cc SMEM wait
//    (~49% duty). Occupancy was self-capped at 2 blocks/CU by launch_bounds(256,2)
//    and grid 768 (3/CU max) -> no independent waves to cover the stall.
//  - fix: split channels across 2 blocks (csel: c 0..127 / 128..255) -> grid 1536
//    = 6 blocks/CU (LDS 6x25KB = 150KB fits exactly); launch_bounds(256,6).
//    6 independent waves/SIMD x ~50% solo duty -> VALU saturates.
//  - halves combine via unsafeAtomicAdd into zeroed s (2 adds, commutative ->
//    deterministic). BN stats moved to bnstats_kernel (needs complete s).
#define CCH 8
#define XS_ELEMS (CCH * 4 * 98)   // 3136 floats = 12544 B per buffer
__global__ __launch_bounds__(256, 6) void conv_kernel(const float* __restrict__ x,
                                                      const float* __restrict__ wt,
                                                      float* __restrict__ s) {
    int phys = blockIdx.x;                       // 1536 blocks
    int blk = (phys & 7) * 192 + (phys >> 3);    // bijective XCD chunking (1536 = 8*192)
    int csel = blk & 1;                          // channel half
    int ogsel = (blk >> 1) & 1;                  // og half
    int np = blk >> 2;                           // 0..383
    int n = np / 48, pair = np % 48;
    int i0 = pair * 2;
    int t = threadIdx.x;
    int wid = t >> 6;                            // wave 0..3
    int lane = t & 63;
    int row = lane >> 5;                         // output row within pair: 0/1
    int k = lane & 31;                           // col group: output cols 3k..3k+2
    int og = __builtin_amdgcn_readfirstlane(ogsel * 4 + wid);   // wave-uniform -> s_load
    const int cbase = csel * 128;

    __shared__ float xs0[XS_ELEMS];
    __shared__ float xs1[XS_ELEMS];

    // ---- precompute per-thread staging source offsets (rel. to xb + c0*HW) ----
    int off[13];
    #pragma unroll
    for (int it = 0; it < 13; it++) {
        if (it == 12 && t >= 64) { off[it] = 0; continue; }
        int gidx = it * 256 + t;                 // 0..3135
        int cc = gidx / 392;
        int rem = gidx - cc * 392;
        int r = rem / 98;
        int col = rem - r * 98;
        int gcol = col - 1;
        if (gcol < 0) gcol = 1; else if (gcol > 95) gcol = 94;
        int ri = i0 - 1 + r;                     // reflected input row
        if (ri < 0) ri = 1; else if (ri > 95) ri = 94;
        off[it] = cc * HW + ri * W_ + gcol;
    }

    float acc[9][3];
    #pragma unroll
    for (int a = 0; a < 9; a++)
        #pragma unroll
        for (int b2 = 0; b2 < 3; b2++) acc[a][b2] = 0.f;

    const float* xb = x + (size_t)n * C_ * HW;
    float* bufA = xs0;                           // buffer being computed
    float* bufB = xs1;                           // buffer being filled

    // ---- prologue: stage chunk cbase into xs0 ----
    {
        const float* src = xb + (size_t)cbase * HW;
        float ld[13];
        #pragma unroll
        for (int it = 0; it < 12; it++) ld[it] = src[off[it]];
        if (t < 64) ld[12] = src[off[12]];
        #pragma unroll
        for (int it = 0; it < 12; it++) xs0[it * 256 + t] = ld[it];
        if (t < 64) xs0[12 * 256 + t] = ld[12];
    }
    __syncthreads();

    for (int c0 = cbase; c0 < cbase + 128; c0 += CCH) {
        // phase A: issue next chunk's global loads (latency hides under compute)
        float ld[13];
        const bool have_next = (c0 + CCH < cbase + 128);
        if (have_next) {
            const float* src = xb + (size_t)(c0 + CCH) * HW;
            #pragma unroll
            for (int it = 0; it < 12; it++) ld[it] = src[off[it]];
            if (t < 64) ld[12] = src[off[12]];
        }
        // phase B: compute 8 channels from bufA (weights via uniform s_load)
        #pragma unroll 1
        for (int cc = 0; cc < CCH; cc++) {
            float xv[3][5];                      // [input row][col], static indices only
            const float* xr = bufA + cc * 392;
            #pragma unroll
            for (int r = 0; r < 3; r++)
                #pragma unroll
                for (int d = 0; d < 5; d++)
                    xv[r][d] = xr[(row + r) * 98 + 3 * k + d];
            const float* wp = wt + ((size_t)og * C_ + (c0 + cc)) * WSTR;  // uniform -> s_load
            #pragma unroll
            for (int oo = 0; oo < 9; oo++) {
                float w0 = wp[oo * 9 + 0], w1 = wp[oo * 9 + 1], w2 = wp[oo * 9 + 2];
                float w3 = wp[oo * 9 + 3], w4 = wp[oo * 9 + 4], w5 = wp[oo * 9 + 5];
                float w6 = wp[oo * 9 + 6], w7 = wp[oo * 9 + 7], w8 = wp[oo * 9 + 8];
                #pragma unroll
                for (int px = 0; px < 3; px++) {
                    acc[oo][px] += xv[0][px] * w0 + xv[0][px + 1] * w1 + xv[0][px + 2] * w2
                                 + xv[1][px] * w3 + xv[1][px + 1] * w4 + xv[1][px + 2] * w5
                                 + xv[2][px] * w6 + xv[2][px + 1] * w7 + xv[2][px + 2] * w8;
                }
            }
        }
        // phase C: write staged regs into bufB, one barrier per chunk
        if (have_next) {
            #pragma unroll
            for (int it = 0; it < 12; it++) bufB[it * 256 + t] = ld[it];
            if (t < 64) bufB[12 * 256 + t] = ld[12];
        }
        __syncthreads();
        float* tmp = bufA; bufA = bufB; bufB = tmp;
    }

    // accumulate this half's contribution into s (2 contributors -> deterministic)
    int i = i0 + row;
    #pragma unroll
    for (int oo = 0; oo < 9; oo++) {
        int o = og * 9 + oo;
        float* sp = s + ((size_t)(n * O_ + o) * H_ + i) * W_ + 3 * k;
        unsafeAtomicAdd(&sp[0], acc[oo][0]);
        unsafeAtomicAdd(&sp[1], acc[oo][1]);
        unsafeAtomicAdd(&sp[2], acc[oo][2]);
    }
}

// ---------------- K5: BN batch stats from completed s ----------------
__global__ __launch_bounds__(256) void bnstats_kernel(const float* __restrict__ s,
                                                      float* __restrict__ bn_stats) {
    int blk = blockIdx.x;                    // O_*B_ = 576
    int o = blk / B_, nn = blk % B_;
    const float4* p = (const float4*)(s + ((size_t)nn * O_ + o) * HW);
    float s1 = 0.f, s2 = 0.f;
    for (int idx = threadIdx.x; idx < HW / 4; idx += 256) {
        float4 v = p[idx];
        s1 += v.x + v.y + v.z + v.w;
        s2 += v.x * v.x + v.y * v.y + v.z * v.z + v.w * v.w;
    }
    #pragma unroll
    for (int m = 32; m >= 1; m >>= 1) {
        s1 += __shfl_xor(s1, m, 64);
        s2 += __shfl_xor(s2, m, 64);
    }
    __shared__ float r1[4], r2[4];
    int wid = threadIdx.x >> 6;
    if ((threadIdx.x & 63) == 0) { r1[wid] = s1; r2[wid] = s2; }
    __syncthreads();
    if (threadIdx.x == 0) {
        atomicAdd(&bn_stats[o * 2 + 0], r1[0] + r1[1] + r1[2] + r1[3]);
        atomicAdd(&bn_stats[o * 2 + 1], r2[0] + r2[1] + r2[2] + r2[3]);
    }
}

// ---------------- K6: BN + softmax(72) + 9-tap gather * gate * sigma ----------------
__global__ __launch_bounds__(256, 2) void out_kernel(const float* __restrict__ x,
                                                     const float* __restrict__ s,
                                                     const float* __restrict__ bn_stats,
                                                     const float* __restrict__ gamma,
                                                     const float* __restrict__ beta,
                                                     const float* __restrict__ gate,
                                                     float* __restrict__ out) {
    int blk = blockIdx.x;                    // 768
    int n = blk / H_, i = blk % H_;
    int t = threadIdx.x;
    __shared__ float sg[O_][W_];             // exp(bn(s)) for this row
    __shared__ float rden[W_];
    __shared__ float gt[G_][3][98];          // gate at reflected tap coords

    int r0 = i - 1; if (r0 < 0) r0 = 1;
    int r2 = i + 1; if (r2 > 95) r2 = 94;
    int rows[3] = { r0, i, r2 };

    for (int idx = t; idx < G_ * 3 * 98; idx += 256) {
        int g = idx / (3 * 98), rem = idx % (3 * 98);
        int r = rem / 98, col = rem % 98;
        int gcol = col - 1;
        if (gcol < 0) gcol = 1; else if (gcol > 95) gcol = 94;
        gt[g][r][col] = gate[((size_t)(n * G_ + g)) * HW + rows[r] * W_ + gcol];
    }
    const float inv = 1.f / (float)NPX;
    for (int idx = t; idx < O_ * W_; idx += 256) {
        int o = idx / W_, j = idx % W_;
        float sum = bn_stats[o * 2], ssq = bn_stats[o * 2 + 1];
        float mean = sum * inv;
        float var = ssq * inv - mean * mean;
        float sc = rsqrtf(var + 1e-5f) * gamma[o];
        float val = (s[((size_t)(n * O_ + o) * H_ + i) * W_ + j] - mean) * sc + beta[o];
        sg[o][j] = expf(val);
    }
    __syncthreads();
    if (t < W_) {
        float d = 0.f;
        #pragma unroll
        for (int o = 0; o < O_; o++) d += sg[o][t];
        rden[t] = 1.f / d;
    }
    __syncthreads();

    const float* xb = x + (size_t)n * C_ * HW;
    for (int idx = t; idx < C_ * W_; idx += 256) {
        int c = idx / W_, j = idx % W_;
        int g = c >> 5;
        const float* xc = xb + (size_t)c * HW;
        int jm1 = j - 1; if (jm1 < 0) jm1 = 1;
        int jp1 = j + 1; if (jp1 > 95) jp1 = 94;
        int cols[3] = { jm1, j, jp1 };
        float acc = 0.f;
        #pragma unroll
        for (int r = 0; r < 3; r++) {
            const float* xr = xc + rows[r] * W_;
            #pragma unroll
            for (int dx = 0; dx < 3; dx++) {
                float xv = xr[cols[dx]];
                float gv = gt[g][r][j + dx];
                float sv = sg[g * 9 + r * 3 + dx][j];
                acc += xv * gv * sv;
            }
        }
        out[((size_t)(n * C_ + c) * H_ + i) * W_ + j] = acc * rden[j];
    }
}

extern "C" void kernel_launch(void* const* d_in, const int* in_sizes, int n_in,
                              void* d_out, int out_size, void* d_ws, size_t ws_size,
                              hipStream_t stream) {
    const float* x      = (const float*)d_in[0];
    const float* sge_w  = (const float*)d_in[1];
    const float* sge_b  = (const float*)d_in[2];
    const float* conv_w = (const float*)d_in[3];
    const float* gamma  = (const float*)d_in[4];
    const float* beta   = (const float*)d_in[5];
    float* out = (float*)d_out;
    float* ws = (float*)d_ws;

    // workspace layout (floats)
    float* sge_stats = ws;            // 128    (sum,sumsq per b*g)
    float* bn_stats  = ws + 128;      // 144    (sum,sumsq per o)
    float* gap       = ws + 272;      // 2048
    float* xng       = ws + 2320;     // 589824 (xn, overwritten in-place by gate)
    float* wt        = ws + 592144;   // 172032 transposed weights (8*256*84)
    float* s         = ws + 764176;   // 5308416 conv output (atomically accumulated)
    // total ~24.3 MB

    hipMemsetAsync(d_ws, 0, 272 * sizeof(float), stream);            // zero stats
    hipMemsetAsync(s, 0, (size_t)B_ * O_ * HW * sizeof(float), stream);  // zero s (atomic acc)
    hipLaunchKernelGGL(wprep_kernel,   dim3(648),          dim3(256), 0, stream, conv_w, wt);
    hipLaunchKernelGGL(gap_kernel,     dim3(B_ * C_),      dim3(256), 0, stream, x, gap);
    hipLaunchKernelGGL(xn_kernel,      dim3(B_ * G_ * 36), dim3(256), 0, stream, x, gap, xng, sge_stats);
    hipLaunchKernelGGL(gate_kernel,    dim3(B_ * G_ * 36), dim3(256), 0, stream, xng, sge_stats, sge_w, sge_b);
    hipLaunchKernelGGL(conv_kernel,    dim3(1536),         dim3(256), 0, stream, x, wt, s);
    hipLaunchKernelGGL(bnstats_kernel, dim3(O_ * B_),      dim3(256), 0, stream, s, bn_stats);
    hipLaunchKernelGGL(out_kernel,     dim3(B_ * H_),      dim3(256), 0, stream, x, s, bn_stats, gamma, beta, xng, out);
}

// Round 7
// 290.583 us; speedup vs baseline: 9.6980x; 2.1494x over previous
//
#include <hip/hip_runtime.h>
#include <hip/hip_bf16.h>

// Problem constants
#define B_  8
#define C_  256
#define H_  96
#define W_  96
#define G_  8
#define CPG 32          // C_/G_
#define KK  9           // 3x3 taps
#define O_  72          // G_*KK conv out channels
#define HW  9216        // H_*W_
#define NPX 73728       // B_*HW (BN population per channel)

typedef short bf16x8 __attribute__((ext_vector_type(8)));
typedef float f32x4 __attribute__((ext_vector_type(4)));

__device__ __forceinline__ unsigned short f2bf(float f) {    // fp32 -> bf16 RNE
    union { float f; unsigned u; } v; v.f = f;
    unsigned r = v.u + 0x7fffu + ((v.u >> 16) & 1u);
    return (unsigned short)(r >> 16);
}
__device__ __forceinline__ float bf2f(unsigned short h) {
    union { float f; unsigned u; } v; v.u = ((unsigned)h) << 16;
    return v.f;
}

// ---------------- K0: weight prepack into B-fragment layout ----------------
// k = tap*256 + c (tap-major). k-step t = tap*8 + cblk covers c = cblk*32..+31.
// bpk[((p*5+nt)*72 + t)*512 + l*8 + j] = split_p( w[o=nt*16+(l&15)][c=cblk*32+(l>>4)*8+j][tap] )
__global__ __launch_bounds__(256) void bprep_kernel(const float* __restrict__ w,
                                                    unsigned short* __restrict__ bpk) {
    int idx = blockIdx.x * 256 + threadIdx.x;        // 2*5*72*512 = 368640
    if (idx >= 368640) return;
    int j = idx & 7;
    int l = (idx >> 3) & 63;
    int w512 = idx >> 9;             // (p*5+nt)*72 + tix
    int tix = w512 % 72;
    int pnt = w512 / 72;
    int p = pnt / 5, nt = pnt % 5;
    int tap = tix >> 3, cblk = tix & 7;
    int o = nt * 16 + (l & 15);
    int c = cblk * 32 + ((l >> 4) << 3) + j;
    unsigned short val = 0;
    if (o < O_) {
        float wv = w[((size_t)o * C_ + c) * KK + tap];
        unsigned short h = f2bf(wv);
        val = (p == 0) ? h : f2bf(wv - bf2f(h));
    }
    bpk[idx] = val;
}

// ---------------- K1: per-(b,c) spatial mean (SGE gap) ----------------
__global__ __launch_bounds__(256) void gap_kernel(const float* __restrict__ x,
                                                  float* __restrict__ gap) {
    int bc = blockIdx.x;                     // 0..2047
    const float4* p = (const float4*)(x + (size_t)bc * HW);
    float sum = 0.f;
    for (int idx = threadIdx.x; idx < HW / 4; idx += 256) {
        float4 v = p[idx];
        sum += v.x + v.y + v.z + v.w;
    }
    #pragma unroll
    for (int m = 32; m >= 1; m >>= 1) sum += __shfl_xor(sum, m, 64);
    __shared__ float red[4];
    int wid = threadIdx.x >> 6;
    if ((threadIdx.x & 63) == 0) red[wid] = sum;
    __syncthreads();
    if (threadIdx.x == 0)
        gap[bc] = (red[0] + red[1] + red[2] + red[3]) * (1.f / (float)HW);
}

// ---------------- K2: xn = sum_ch xg*gap, + per-(b,g) sum/sumsq ----------------
__global__ __launch_bounds__(256) void xn_kernel(const float* __restrict__ x,
                                                 const float* __restrict__ gap,
                                                 float* __restrict__ xng,
                                                 float* __restrict__ sge_stats) {
    int blk = blockIdx.x;                    // B_*G_*36 = 2304
    int bg = blk / 36, chunk = blk % 36;
    int b = bg >> 3, g = bg & 7;
    int p = chunk * 256 + threadIdx.x;
    const float* xbase = x + ((size_t)b * C_ + g * CPG) * HW + p;
    const float* gp = gap + b * C_ + g * CPG;
    float v = 0.f;
    #pragma unroll
    for (int ch = 0; ch < CPG; ch++) v += xbase[(size_t)ch * HW] * gp[ch];
    xng[(size_t)bg * HW + p] = v;
    float v1 = v, v2 = v * v;
    #pragma unroll
    for (int m = 32; m >= 1; m >>= 1) {
        v1 += __shfl_xor(v1, m, 64);
        v2 += __shfl_xor(v2, m, 64);
    }
    __shared__ float r1[4], r2[4];
    int wid = threadIdx.x >> 6;
    if ((threadIdx.x & 63) == 0) { r1[wid] = v1; r2[wid] = v2; }
    __syncthreads();
    if (threadIdx.x == 0) {
        atomicAdd(&sge_stats[bg * 2 + 0], r1[0] + r1[1] + r1[2] + r1[3]);
        atomicAdd(&sge_stats[bg * 2 + 1], r2[0] + r2[1] + r2[2] + r2[3]);
    }
}

// ---------------- K3: gate = sigmoid(normalized(xn)*w + b), in place ----------------
__global__ __launch_bounds__(256) void gate_kernel(float* __restrict__ xng,
                                                   const float* __restrict__ stats,
                                                   const float* __restrict__ sw,
                                                   const float* __restrict__ sb) {
    int idx = blockIdx.x * 256 + threadIdx.x;    // exactly 589824
    int bg = idx / HW;
    int g = bg & 7;
    float sum = stats[bg * 2], sumsq = stats[bg * 2 + 1];
    float mean = sum * (1.f / (float)HW);
    float var = (sumsq - sum * mean) * (1.f / (float)(HW - 1));
    var = fmaxf(var, 0.f);
    float sd = sqrtf(var) + 1e-5f;
    float tv = (xng[idx] - mean) / sd * sw[g] + sb[g];
    xng[idx] = 1.f / (1.f + expf(-tv));
}

// ---------------- K4: conv as implicit GEMM via MFMA, split-bf16 (3 terms) ----------------
// Block = (n, row-pair). 4 waves = (row rw, M-half mh); wave: 3 M-tiles(16px) x 5 N-tiles(16o).
// LDS: x chunk fp32 [4 rows][98 cols][32 cc], XOR-swizzled (u ^= col&7) -> conflict-free.
// A-frag: lane l, elem j = xs[rw+dr][colb+m*16+dc][(l>>4)*8+j]; split to hi/lo at read.
// B-frag: prepacked global (L3-resident), coalesced 16B/lane.
// acc[m][nt] accumulates ALL 72 k-steps (8 chunks x 9 taps).
#define SWZ(RR, COL, CC) ((((RR) * 98 + (COL)) << 5) + (((((CC) >> 2) ^ ((COL) & 7))) << 2) + ((CC) & 3))

__global__ __launch_bounds__(256, 2) void conv_kernel(const float* __restrict__ x,
                                                      const unsigned short* __restrict__ bpk,
                                                      float* __restrict__ s,
                                                      float* __restrict__ bn_stats) {
    __shared__ float xs[4 * 98 * 32];            // 50176 B
    int phys = blockIdx.x;                       // 384
    int blk = (phys & 7) * 48 + (phys >> 3);     // bijective XCD chunking
    int n = blk / 48, pair = blk % 48;
    int i0 = pair * 2;
    int t = threadIdx.x;
    int l = t & 63, wave = t >> 6;
    int rw = wave & 1, mh = wave >> 1;
    int l15 = l & 15, lg = l >> 4;
    int colb = mh * 48 + l15;
    const float* xb = x + (size_t)n * C_ * HW;

    // staging mapping: thread -> (cc, rr, q); 12 float4 interior + 1 edge scalar
    int scc = t & 31, srr = (t >> 5) & 3, sq = t >> 7;
    int sri = i0 - 1 + srr;
    if (sri < 0) sri = 1; else if (sri > 95) sri = 94;
    const float* sbase = xb + (size_t)scc * HW + sri * W_;
    int wbase = srr * 98;
    int wc2 = scc >> 2, wc3 = scc & 3;

    f32x4 acc[3][5];
    #pragma unroll
    for (int m = 0; m < 3; m++)
        #pragma unroll
        for (int nt = 0; nt < 5; nt++)
            #pragma unroll
            for (int e = 0; e < 4; e++) acc[m][nt][e] = 0.f;

    f32x4 sld[12]; float sed;

    // prologue: stage chunk 0
    {
        #pragma unroll
        for (int m2 = 0; m2 < 12; m2++)
            sld[m2] = *(const f32x4*)(sbase + (sq * 12 + m2) * 4);
        sed = sbase[sq ? 94 : 1];
        #pragma unroll
        for (int m2 = 0; m2 < 12; m2++)
            #pragma unroll
            for (int e = 0; e < 4; e++) {
                int col = (sq * 12 + m2) * 4 + 1 + e;
                xs[((wbase + col) << 5) + ((wc2 ^ (col & 7)) << 2) + wc3] = sld[m2][e];
            }
        int colE = sq ? 97 : 0;
        xs[((wbase + colE) << 5) + ((wc2 ^ (colE & 7)) << 2) + wc3] = sed;
    }
    __syncthreads();

    for (int ch = 0; ch < 8; ch++) {
        if (ch < 7) {                             // T14: issue next-chunk loads early
            const float* src = sbase + (size_t)(ch + 1) * 32 * HW;
            #pragma unroll
            for (int m2 = 0; m2 < 12; m2++)
                sld[m2] = *(const f32x4*)(src + (sq * 12 + m2) * 4);
            sed = src[sq ? 94 : 1];
        }
        #pragma unroll 1
        for (int tap = 0; tap < 9; tap++) {
            int dr = tap / 3, dc = tap - dr * 3;
            int tix = tap * 8 + ch;
            int bo = tix * 512 + (l << 3);
            bf16x8 bh[5], blo[5];
            #pragma unroll
            for (int nt = 0; nt < 5; nt++)
                bh[nt] = *(const bf16x8*)(bpk + nt * 36864 + bo);
            #pragma unroll
            for (int nt = 0; nt < 5; nt++)
                blo[nt] = *(const bf16x8*)(bpk + 184320 + nt * 36864 + bo);
            int rr = rw + dr;
            bf16x8 ah[3], al[3];
            #pragma unroll
            for (int m = 0; m < 3; m++) {
                int col = colb + m * 16 + dc;
                int fb = (rr * 98 + col) << 5;
                int sw = col & 7;
                int g2 = lg << 1;
                f32x4 p0 = *(const f32x4*)&xs[fb + ((g2 ^ sw) << 2)];
                f32x4 p1 = *(const f32x4*)&xs[fb + (((g2 + 1) ^ sw) << 2)];
                #pragma unroll
                for (int e = 0; e < 8; e++) {
                    float xv = (e < 4) ? p0[e & 3] : p1[e & 3];
                    unsigned short h = f2bf(xv);
                    float r2 = xv - bf2f(h);
                    ah[m][e] = (short)h;
                    al[m][e] = (short)f2bf(r2);
                }
            }
            #pragma unroll
            for (int m = 0; m < 3; m++)
                #pragma unroll
                for (int nt = 0; nt < 5; nt++) {
                    acc[m][nt] = __builtin_amdgcn_mfma_f32_16x16x32_bf16(ah[m], bh[nt],  acc[m][nt], 0, 0, 0);
                    acc[m][nt] = __builtin_amdgcn_mfma_f32_16x16x32_bf16(ah[m], blo[nt], acc[m][nt], 0, 0, 0);
                    acc[m][nt] = __builtin_amdgcn_mfma_f32_16x16x32_bf16(al[m], bh[nt],  acc[m][nt], 0, 0, 0);
                }
        }
        __syncthreads();                          // all reads of xs done
        if (ch < 7) {
            #pragma unroll
            for (int m2 = 0; m2 < 12; m2++)
                #pragma unroll
                for (int e = 0; e < 4; e++) {
                    int col = (sq * 12 + m2) * 4 + 1 + e;
                    xs[((wbase + col) << 5) + ((wc2 ^ (col & 7)) << 2) + wc3] = sld[m2][e];
                }
            int colE = sq ? 97 : 0;
            xs[((wbase + colE) << 5) + ((wc2 ^ (colE & 7)) << 2) + wc3] = sed;
            __syncthreads();                      // writes visible
        }
    }

    // store s (D: row=(l>>4)*4+r -> px, col=l&15 -> o) + BN stats (shuffle+atomic)
    int i = i0 + rw;
    #pragma unroll
    for (int nt = 0; nt < 5; nt++) {
        int o = nt * 16 + l15;
        float v1 = 0.f, v2 = 0.f;
        #pragma unroll
        for (int m = 0; m < 3; m++)
            #pragma unroll
            for (int r = 0; r < 4; r++) {
                float d = acc[m][nt][r];
                v1 += d; v2 += d * d;
                if (o < O_) {
                    int px = mh * 48 + m * 16 + (lg << 2) + r;
                    s[((size_t)(n * O_ + o) * H_ + i) * W_ + px] = d;
                }
            }
        v1 += __shfl_xor(v1, 16, 64); v1 += __shfl_xor(v1, 32, 64);
        v2 += __shfl_xor(v2, 16, 64); v2 += __shfl_xor(v2, 32, 64);
        if (l < 16 && o < O_) {
            atomicAdd(&bn_stats[o * 2 + 0], v1);
            atomicAdd(&bn_stats[o * 2 + 1], v2);
        }
    }
}

// ---------------- K6: BN + softmax(72) + 9-tap gather * gate * sigma ----------------
__global__ __launch_bounds__(256, 2) void out_kernel(const float* __restrict__ x,
                                                     const float* __restrict__ s,
                                                     const float* __restrict__ bn_stats,
                                                     const float* __restrict__ gamma,
                                                     const float* __restrict__ beta,
                                                     const float* __restrict__ gate,
                                                     float* __restrict__ out) {
    int blk = blockIdx.x;                    // 768
    int n = blk / H_, i = blk % H_;
    int t = threadIdx.x;
    __shared__ float sg[O_][W_];             // exp(bn(s)) for this row
    __shared__ float rden[W_];
    __shared__ float gt[G_][3][98];          // gate at reflected tap coords

    int r0 = i - 1; if (r0 < 0) r0 = 1;
    int r2 = i + 1; if (r2 > 95) r2 = 94;
    int rows[3] = { r0, i, r2 };

    for (int idx = t; idx < G_ * 3 * 98; idx += 256) {
        int g = idx / (3 * 98), rem = idx % (3 * 98);
        int r = rem / 98, col = rem % 98;
        int gcol = col - 1;
        if (gcol < 0) gcol = 1; else if (gcol > 95) gcol = 94;
        gt[g][r][col] = gate[((size_t)(n * G_ + g)) * HW + rows[r] * W_ + gcol];
    }
    const float inv = 1.f / (float)NPX;
    for (int idx = t; idx < O_ * W_; idx += 256) {
        int o = idx / W_, j = idx % W_;
        float sum = bn_stats[o * 2], ssq = bn_stats[o * 2 + 1];
        float mean = sum * inv;
        float var = ssq * inv - mean * mean;
        float sc = rsqrtf(var + 1e-5f) * gamma[o];
        float val = (s[((size_t)(n * O_ + o) * H_ + i) * W_ + j] - mean) * sc + beta[o];
        sg[o][j] = expf(val);
    }
    __syncthreads();
    if (t < W_) {
        float d = 0.f;
        #pragma unroll
        for (int o = 0; o < O_; o++) d += sg[o][t];
        rden[t] = 1.f / d;
    }
    __syncthreads();

    const float* xb = x + (size_t)n * C_ * HW;
    for (int idx = t; idx < C_ * W_; idx += 256) {
        int c = idx / W_, j = idx % W_;
        int g = c >> 5;
        const float* xc = xb + (size_t)c * HW;
        int jm1 = j - 1; if (jm1 < 0) jm1 = 1;
        int jp1 = j + 1; if (jp1 > 95) jp1 = 94;
        int cols[3] = { jm1, j, jp1 };
        float acc = 0.f;
        #pragma unroll
        for (int r = 0; r < 3; r++) {
            const float* xr = xc + rows[r] * W_;
            #pragma unroll
            for (int dx = 0; dx < 3; dx++) {
                float xv = xr[cols[dx]];
                float gv = gt[g][r][j + dx];
                float sv = sg[g * 9 + r * 3 + dx][j];
                acc += xv * gv * sv;
            }
        }
        out[((size_t)(n * C_ + c) * H_ + i) * W_ + j] = acc * rden[j];
    }
}

extern "C" void kernel_launch(void* const* d_in, const int* in_sizes, int n_in,
                              void* d_out, int out_size, void* d_ws, size_t ws_size,
                              hipStream_t stream) {
    const float* x      = (const float*)d_in[0];
    const float* sge_w  = (const float*)d_in[1];
    const float* sge_b  = (const float*)d_in[2];
    const float* conv_w = (const float*)d_in[3];
    const float* gamma  = (const float*)d_in[4];
    const float* beta   = (const float*)d_in[5];
    float* out = (float*)d_out;
    float* ws = (float*)d_ws;

    // workspace layout (floats)
    float* sge_stats = ws;            // 128    (sum,sumsq per b*g)
    float* bn_stats  = ws + 128;      // 144    (sum,sumsq per o)
    float* gap       = ws + 272;      // 2048
    float* xng       = ws + 2320;     // 589824 (xn, overwritten in-place by gate)
    unsigned short* bpk = (unsigned short*)(ws + 592144);  // 368640 ushorts (184320 floats)
    float* s         = ws + 776464;   // 5308416 conv output
    // total ~24.3 MB

    hipMemsetAsync(d_ws, 0, 272 * sizeof(float), stream);  // zero stats each call
    hipLaunchKernelGGL(bprep_kernel, dim3(1440),        dim3(256), 0, stream, conv_w, bpk);
    hipLaunchKernelGGL(gap_kernel,   dim3(B_ * C_),     dim3(256), 0, stream, x, gap);
    hipLaunchKernelGGL(xn_kernel,    dim3(B_ * G_ * 36),dim3(256), 0, stream, x, gap, xng, sge_stats);
    hipLaunchKernelGGL(gate_kernel,  dim3(B_ * G_ * 36),dim3(256), 0, stream, xng, sge_stats, sge_w, sge_b);
    hipLaunchKernelGGL(conv_kernel,  dim3(384),         dim3(256), 0, stream, x, bpk, s, bn_stats);
    hipLaunchKernelGGL(out_kernel,   dim3(B_ * H_),     dim3(256), 0, stream, x, s, bn_stats, gamma, beta, xng, out);
}